// Round 1
// baseline (783.675 us; speedup 1.0000x reference)
//
#include <hip/hip_runtime.h>
#include <hip/hip_bf16.h>
#include <cstdint>

#define IN_DIM 128
#define OUT_DIM 64
#define FEATD 50
#define NEG_SLOPE 0.01f

typedef unsigned int uint32;

// K0: v3[j] = sum_o W_attn[128+o] * W_feat[o*FEATD+j]
__global__ __launch_bounds__(64) void k_v3(const float* __restrict__ W_feat,
                                           const float* __restrict__ W_attn,
                                           float* __restrict__ v3) {
  int j = threadIdx.x;
  if (j < FEATD) {
    float s = 0.f;
    #pragma unroll
    for (int o = 0; o < OUT_DIM; ++o)
      s = fmaf(W_attn[2 * OUT_DIM + o], W_feat[o * FEATD + j], s);
    v3[j] = s;
  }
}

// K1: per node (lane = node): z row (words), s1 = z.wa1 (words), s2 = z.wa2 (sents)
__global__ __launch_bounds__(256) void k_node(const float* __restrict__ h,
    const float* __restrict__ W_fc, const float* __restrict__ W_attn,
    float* __restrict__ z, float* __restrict__ s1, float* __restrict__ s2,
    int n_words, int n_nodes) {
  __shared__ __align__(16) float Wl[OUT_DIM * IN_DIM];
  __shared__ float wal[2 * OUT_DIM];
  for (int i = threadIdx.x; i < OUT_DIM * IN_DIM; i += 256) Wl[i] = W_fc[i];
  if (threadIdx.x < 2 * OUT_DIM) wal[threadIdx.x] = W_attn[threadIdx.x];
  __syncthreads();

  int node = blockIdx.x * 256 + threadIdx.x;
  int nc = node < n_nodes ? node : (n_nodes - 1);
  const float* hrow = h + (size_t)nc * IN_DIM;

  float acc[OUT_DIM];
  #pragma unroll
  for (int o = 0; o < OUT_DIM; ++o) acc[o] = 0.f;

  #pragma unroll 1
  for (int c = 0; c < IN_DIM / 16; ++c) {  // 8 chunks of 16 input features
    float hk[16];
    #pragma unroll
    for (int k = 0; k < 4; ++k) {
      float4 t = *(const float4*)(hrow + c * 16 + k * 4);
      hk[k * 4 + 0] = t.x; hk[k * 4 + 1] = t.y;
      hk[k * 4 + 2] = t.z; hk[k * 4 + 3] = t.w;
    }
    #pragma unroll
    for (int o = 0; o < OUT_DIM; ++o) {
      const float4* wr = (const float4*)&Wl[o * IN_DIM + c * 16];  // uniform -> LDS broadcast
      #pragma unroll
      for (int k = 0; k < 4; ++k) {
        float4 w = wr[k];
        acc[o] = fmaf(hk[k * 4 + 0], w.x, acc[o]);
        acc[o] = fmaf(hk[k * 4 + 1], w.y, acc[o]);
        acc[o] = fmaf(hk[k * 4 + 2], w.z, acc[o]);
        acc[o] = fmaf(hk[k * 4 + 3], w.w, acc[o]);
      }
    }
  }

  if (node < n_words) {
    float s = 0.f;
    #pragma unroll
    for (int o = 0; o < OUT_DIM; ++o) s = fmaf(acc[o], wal[o], s);
    s1[node] = s;
    float* zr = z + (size_t)node * OUT_DIM;
    #pragma unroll
    for (int k = 0; k < OUT_DIM / 4; ++k) {
      float4 t;
      t.x = acc[4 * k]; t.y = acc[4 * k + 1];
      t.z = acc[4 * k + 2]; t.w = acc[4 * k + 3];
      *(float4*)(zr + 4 * k) = t;
    }
  } else if (node < n_nodes) {
    float s = 0.f;
    #pragma unroll
    for (int o = 0; o < OUT_DIM; ++o) s = fmaf(acc[o], wal[OUT_DIM + o], s);
    s2[node - n_words] = s;
  }
}

// K2: per edge: f = tfidf.v3 ; e = leaky(s1[src]+s2[dst]+f); ex = exp(e);
//     denom[dst] += ex; cnt[dst] += 1
__global__ __launch_bounds__(256) void k_edge(const float* __restrict__ tfidf,
    const int* __restrict__ src, const int* __restrict__ dst,
    const float* __restrict__ s1, const float* __restrict__ s2,
    const float* __restrict__ v3, float* __restrict__ ex,
    float* __restrict__ denom, uint32* __restrict__ cnt, int E) {
  __shared__ float v3l[FEATD];
  if (threadIdx.x < FEATD) v3l[threadIdx.x] = v3[threadIdx.x];
  __syncthreads();
  int e = blockIdx.x * 256 + threadIdx.x;
  if (e >= E) return;
  const float* row = tfidf + (size_t)e * FEATD;
  float f = 0.f;
  #pragma unroll
  for (int k = 0; k < FEATD / 2; ++k) {
    float2 v = *(const float2*)(row + 2 * k);
    f = fmaf(v.x, v3l[2 * k], f);
    f = fmaf(v.y, v3l[2 * k + 1], f);
  }
  int sidx = src[e], d = dst[e];
  float ev = s1[sidx] + s2[d] + f;
  ev = ev >= 0.f ? ev : NEG_SLOPE * ev;
  float exv = __expf(ev);
  ex[e] = exv;
  atomicAdd(&denom[d], exv);
  atomicAdd(&cnt[d], 1u);
}

// K3: exclusive scan of cnt[0..n) -> off[0..n]
__global__ __launch_bounds__(1024) void k_scan(const uint32* __restrict__ cnt,
    uint32* __restrict__ off, int n) {
  __shared__ uint32 part[1024];
  int t = threadIdx.x;
  int CH = (n + 1023) >> 10;
  int base = t * CH;
  uint32 s = 0;
  for (int k = 0; k < CH; ++k) { int i = base + k; if (i < n) s += cnt[i]; }
  part[t] = s;
  __syncthreads();
  uint32 x = s;
  for (int d = 1; d < 1024; d <<= 1) {
    uint32 v = (t >= d) ? part[t - d] : 0u;
    __syncthreads();
    x += v;
    part[t] = x;
    __syncthreads();
  }
  uint32 run = (t > 0) ? part[t - 1] : 0u;
  for (int k = 0; k < CH; ++k) {
    int i = base + k;
    if (i < n) { off[i] = run; run += cnt[i]; }
  }
  if (t == 1023) off[n] = part[1023];
}

// K4: bucket edges by dst: perm[off[d] + pos] = e
__global__ __launch_bounds__(256) void k_place(const int* __restrict__ dst,
    const uint32* __restrict__ off, uint32* __restrict__ cursor,
    uint32* __restrict__ perm, int E) {
  int e = blockIdx.x * 256 + threadIdx.x;
  if (e >= E) return;
  int d = dst[e];
  uint32 p = atomicAdd(&cursor[d], 1u);
  perm[off[d] + p] = (uint32)e;
}

// K5: block per sentence: out[s][:] = sum_e (ex[e]/denom[s]) * z[src[e]][:]
__global__ __launch_bounds__(256) void k_agg(const float* __restrict__ z,
    const float* __restrict__ ex, const int* __restrict__ src,
    const uint32* __restrict__ off, const float* __restrict__ denom,
    const uint32* __restrict__ perm, float* __restrict__ out) {
  int s = blockIdx.x;
  int w = threadIdx.x >> 6, lane = threadIdx.x & 63;
  uint32 j0 = off[s], j1 = off[s + 1];
  float rd = __frcp_rn(denom[s]);  // inf when empty segment; loop not entered
  float acc = 0.f;
  for (uint32 j = j0 + w; j < j1; j += 4) {
    uint32 e = perm[j];
    float a = ex[e] * rd;
    int sv = src[e];
    acc = fmaf(a, z[(size_t)sv * OUT_DIM + lane], acc);
  }
  __shared__ float red[4][64];
  red[w][lane] = acc;
  __syncthreads();
  if (threadIdx.x < 64) {
    out[(size_t)s * OUT_DIM + lane] =
        red[0][lane] + red[1][lane] + red[2][lane] + red[3][lane];
  }
}

extern "C" void kernel_launch(void* const* d_in, const int* in_sizes, int n_in,
                              void* d_out, int out_size, void* d_ws, size_t ws_size,
                              hipStream_t stream) {
  const float* h      = (const float*)d_in[0];
  const float* tfidf  = (const float*)d_in[1];
  const float* W_fc   = (const float*)d_in[2];
  const float* W_feat = (const float*)d_in[3];
  const float* W_attn = (const float*)d_in[4];
  const int*   src    = (const int*)d_in[5];
  const int*   dst    = (const int*)d_in[6];

  int n_nodes = in_sizes[0] / IN_DIM;   // 220000
  int E       = in_sizes[5];            // 2,000,000
  int n_sents = out_size / OUT_DIM;     // 20000
  int n_words = n_nodes - n_sents;      // 200000
  float* out = (float*)d_out;

  char* ws = (char*)d_ws;
  size_t ofs = 0;
  auto alloc = [&](size_t bytes) -> char* {
    char* p = ws + ofs;
    ofs += (bytes + 255) / 256 * 256;
    return p;
  };
  float*  z      = (float*)alloc((size_t)n_words * OUT_DIM * 4);
  float*  s1     = (float*)alloc((size_t)n_words * 4);
  float*  s2     = (float*)alloc((size_t)n_sents * 4);
  float*  exbuf  = (float*)alloc((size_t)E * 4);
  uint32* perm   = (uint32*)alloc((size_t)E * 4);
  float*  denom  = (float*)alloc((size_t)n_sents * 4);
  uint32* cnt    = (uint32*)alloc((size_t)n_sents * 4);
  uint32* offs   = (uint32*)alloc((size_t)(n_sents + 1) * 4);
  uint32* cursor = (uint32*)alloc((size_t)n_sents * 4);
  float*  v3     = (float*)alloc(FEATD * 4);
  (void)ws_size; (void)n_in;

  hipMemsetAsync(denom, 0, (size_t)n_sents * 4, stream);
  hipMemsetAsync(cnt, 0, (size_t)n_sents * 4, stream);
  hipMemsetAsync(cursor, 0, (size_t)n_sents * 4, stream);

  k_v3<<<1, 64, 0, stream>>>(W_feat, W_attn, v3);
  k_node<<<(n_nodes + 255) / 256, 256, 0, stream>>>(h, W_fc, W_attn, z, s1, s2,
                                                    n_words, n_nodes);
  k_edge<<<(E + 255) / 256, 256, 0, stream>>>(tfidf, src, dst, s1, s2, v3,
                                              exbuf, denom, cnt, E);
  k_scan<<<1, 1024, 0, stream>>>(cnt, offs, n_sents);
  k_place<<<(E + 255) / 256, 256, 0, stream>>>(dst, offs, cursor, perm, E);
  k_agg<<<n_sents, 256, 0, stream>>>(z, exbuf, src, offs, denom, perm, out);
}

// Round 2
// 479.969 us; speedup vs baseline: 1.6328x; 1.6328x over previous
//
#include <hip/hip_runtime.h>
#include <hip/hip_bf16.h>
#include <hip/hip_fp16.h>
#include <cstdint>

#define IN_DIM 128
#define OUT_DIM 64
#define FEATD 50
#define NEG_SLOPE 0.01f

typedef unsigned int uint32;

// K0: v3[j] = sum_o W_attn[128+o] * W_feat[o*FEATD+j]
__global__ __launch_bounds__(64) void k_v3(const float* __restrict__ W_feat,
                                           const float* __restrict__ W_attn,
                                           float* __restrict__ v3) {
  int j = threadIdx.x;
  if (j < FEATD) {
    float s = 0.f;
    #pragma unroll
    for (int o = 0; o < OUT_DIM; ++o)
      s = fmaf(W_attn[2 * OUT_DIM + o], W_feat[o * FEATD + j], s);
    v3[j] = s;
  }
}

// K1: per node (lane = node): z row in fp16 (words), s1 = z.wa1 (words), s2 = z.wa2 (sents)
__global__ __launch_bounds__(256) void k_node(const float* __restrict__ h,
    const float* __restrict__ W_fc, const float* __restrict__ W_attn,
    __half* __restrict__ z, float* __restrict__ s1, float* __restrict__ s2,
    int n_words, int n_nodes) {
  __shared__ __align__(16) float Wl[OUT_DIM * IN_DIM];
  __shared__ float wal[2 * OUT_DIM];
  for (int i = threadIdx.x; i < OUT_DIM * IN_DIM; i += 256) Wl[i] = W_fc[i];
  if (threadIdx.x < 2 * OUT_DIM) wal[threadIdx.x] = W_attn[threadIdx.x];
  __syncthreads();

  int node = blockIdx.x * 256 + threadIdx.x;
  int nc = node < n_nodes ? node : (n_nodes - 1);
  const float* hrow = h + (size_t)nc * IN_DIM;

  float acc[OUT_DIM];
  #pragma unroll
  for (int o = 0; o < OUT_DIM; ++o) acc[o] = 0.f;

  #pragma unroll 1
  for (int c = 0; c < IN_DIM / 16; ++c) {  // 8 chunks of 16 input features
    float hk[16];
    #pragma unroll
    for (int k = 0; k < 4; ++k) {
      float4 t = *(const float4*)(hrow + c * 16 + k * 4);
      hk[k * 4 + 0] = t.x; hk[k * 4 + 1] = t.y;
      hk[k * 4 + 2] = t.z; hk[k * 4 + 3] = t.w;
    }
    #pragma unroll
    for (int o = 0; o < OUT_DIM; ++o) {
      const float4* wr = (const float4*)&Wl[o * IN_DIM + c * 16];  // uniform -> LDS broadcast
      #pragma unroll
      for (int k = 0; k < 4; ++k) {
        float4 w = wr[k];
        acc[o] = fmaf(hk[k * 4 + 0], w.x, acc[o]);
        acc[o] = fmaf(hk[k * 4 + 1], w.y, acc[o]);
        acc[o] = fmaf(hk[k * 4 + 2], w.z, acc[o]);
        acc[o] = fmaf(hk[k * 4 + 3], w.w, acc[o]);
      }
    }
  }

  if (node < n_words) {
    float s = 0.f;
    #pragma unroll
    for (int o = 0; o < OUT_DIM; ++o) s = fmaf(acc[o], wal[o], s);
    s1[node] = s;
    // pack 64 fp16 = 128 B = 8 uint4 stores
    uint32 pk[32];
    #pragma unroll
    for (int k = 0; k < 32; ++k) {
      __half2 t = __floats2half2_rn(acc[2 * k], acc[2 * k + 1]);
      pk[k] = *(uint32*)&t;
    }
    uint4* zr4 = (uint4*)(z + (size_t)node * OUT_DIM);
    #pragma unroll
    for (int k = 0; k < 8; ++k)
      zr4[k] = make_uint4(pk[4 * k], pk[4 * k + 1], pk[4 * k + 2], pk[4 * k + 3]);
  } else if (node < n_nodes) {
    float s = 0.f;
    #pragma unroll
    for (int o = 0; o < OUT_DIM; ++o) s = fmaf(acc[o], wal[OUT_DIM + o], s);
    s2[node - n_words] = s;
  }
}

// K2: histogram of dst
__global__ __launch_bounds__(256) void k_hist(const int* __restrict__ dst,
                                              uint32* __restrict__ cnt, int E) {
  int e = blockIdx.x * 256 + threadIdx.x;
  if (e < E) atomicAdd(&cnt[dst[e]], 1u);
}

// K3: exclusive scan of cnt[0..n) -> off[0..n]
__global__ __launch_bounds__(1024) void k_scan(const uint32* __restrict__ cnt,
    uint32* __restrict__ off, int n) {
  __shared__ uint32 part[1024];
  int t = threadIdx.x;
  int CH = (n + 1023) >> 10;
  int base = t * CH;
  uint32 s = 0;
  for (int k = 0; k < CH; ++k) { int i = base + k; if (i < n) s += cnt[i]; }
  part[t] = s;
  __syncthreads();
  uint32 x = s;
  for (int d = 1; d < 1024; d <<= 1) {
    uint32 v = (t >= d) ? part[t - d] : 0u;
    __syncthreads();
    x += v;
    part[t] = x;
    __syncthreads();
  }
  uint32 run = (t > 0) ? part[t - 1] : 0u;
  for (int k = 0; k < CH; ++k) {
    int i = base + k;
    if (i < n) { off[i] = run; run += cnt[i]; }
  }
  if (t == 1023) off[n] = part[1023];
}

// K4: per edge: f = tfidf.v3 ; e = leaky(s1[src]+s2[dst]+f);
//     scatter {exp(e), src} into dst-sorted pair array
__global__ __launch_bounds__(256) void k_edge(const float* __restrict__ tfidf,
    const int* __restrict__ src, const int* __restrict__ dst,
    const float* __restrict__ s1, const float* __restrict__ s2,
    const float* __restrict__ v3, const uint32* __restrict__ off,
    uint32* __restrict__ cursor, float2* __restrict__ pair, int E) {
  __shared__ float v3l[FEATD];
  if (threadIdx.x < FEATD) v3l[threadIdx.x] = v3[threadIdx.x];
  __syncthreads();
  int e = blockIdx.x * 256 + threadIdx.x;
  if (e >= E) return;
  const float* row = tfidf + (size_t)e * FEATD;
  float f = 0.f;
  #pragma unroll
  for (int k = 0; k < FEATD / 2; ++k) {
    float2 v = *(const float2*)(row + 2 * k);
    f = fmaf(v.x, v3l[2 * k], f);
    f = fmaf(v.y, v3l[2 * k + 1], f);
  }
  int sidx = src[e], d = dst[e];
  float ev = s1[sidx] + s2[d] + f;
  ev = ev >= 0.f ? ev : NEG_SLOPE * ev;
  float exv = __expf(ev);
  uint32 p = atomicAdd(&cursor[d], 1u);
  float2 pr;
  pr.x = exv;
  pr.y = __int_as_float(sidx);
  pair[off[d] + p] = pr;
}

// K5: block per sentence; 4 waves take contiguous chunks; unroll 8 for MLP.
__global__ __launch_bounds__(256) void k_agg(const __half* __restrict__ z,
    const float2* __restrict__ pair, const uint32* __restrict__ off,
    float* __restrict__ out) {
  int s = blockIdx.x;
  int w = threadIdx.x >> 6, lane = threadIdx.x & 63;
  uint32 j0 = off[s], j1 = off[s + 1];
  uint32 n = j1 - j0;
  uint32 q = n >> 2, r = n & 3;
  uint32 b0 = j0 + w * q + (((uint32)w < r) ? (uint32)w : r);
  uint32 b1 = b0 + q + (((uint32)w < r) ? 1u : 0u);

  float acc = 0.f, sa = 0.f;
  uint32 j = b0;
  for (; j + 8 <= b1; j += 8) {
    float2 p[8];
    #pragma unroll
    for (int k = 0; k < 8; ++k) p[k] = pair[j + k];
    float v[8];
    #pragma unroll
    for (int k = 0; k < 8; ++k)
      v[k] = __half2float(z[(size_t)(uint32)__float_as_int(p[k].y) * OUT_DIM + lane]);
    #pragma unroll
    for (int k = 0; k < 8; ++k) { acc = fmaf(p[k].x, v[k], acc); sa += p[k].x; }
  }
  for (; j + 4 <= b1; j += 4) {
    float2 p[4];
    #pragma unroll
    for (int k = 0; k < 4; ++k) p[k] = pair[j + k];
    float v[4];
    #pragma unroll
    for (int k = 0; k < 4; ++k)
      v[k] = __half2float(z[(size_t)(uint32)__float_as_int(p[k].y) * OUT_DIM + lane]);
    #pragma unroll
    for (int k = 0; k < 4; ++k) { acc = fmaf(p[k].x, v[k], acc); sa += p[k].x; }
  }
  for (; j < b1; ++j) {
    float2 p = pair[j];
    float v = __half2float(z[(size_t)(uint32)__float_as_int(p.y) * OUT_DIM + lane]);
    acc = fmaf(p.x, v, acc);
    sa += p.x;
  }

  __shared__ float red[4][64];
  __shared__ float sred[4];
  red[w][lane] = acc;
  if (lane == 0) sred[w] = sa;
  __syncthreads();
  if (threadIdx.x < 64) {
    float tot = (red[0][lane] + red[1][lane]) + (red[2][lane] + red[3][lane]);
    float d = (sred[0] + sred[1]) + (sred[2] + sred[3]);
    out[(size_t)s * OUT_DIM + lane] = (d > 0.f) ? (tot / d) : 0.f;
  }
}

extern "C" void kernel_launch(void* const* d_in, const int* in_sizes, int n_in,
                              void* d_out, int out_size, void* d_ws, size_t ws_size,
                              hipStream_t stream) {
  const float* h      = (const float*)d_in[0];
  const float* tfidf  = (const float*)d_in[1];
  const float* W_fc   = (const float*)d_in[2];
  const float* W_feat = (const float*)d_in[3];
  const float* W_attn = (const float*)d_in[4];
  const int*   src    = (const int*)d_in[5];
  const int*   dst    = (const int*)d_in[6];

  int n_nodes = in_sizes[0] / IN_DIM;   // 220000
  int E       = in_sizes[5];            // 2,000,000
  int n_sents = out_size / OUT_DIM;     // 20000
  int n_words = n_nodes - n_sents;      // 200000
  float* out = (float*)d_out;

  char* ws = (char*)d_ws;
  size_t ofs = 0;
  auto alloc = [&](size_t bytes) -> char* {
    char* p = ws + ofs;
    ofs += (bytes + 255) / 256 * 256;
    return p;
  };
  __half* z      = (__half*)alloc((size_t)n_words * OUT_DIM * 2);
  float*  s1     = (float*)alloc((size_t)n_words * 4);
  float*  s2     = (float*)alloc((size_t)n_sents * 4);
  float2* pair   = (float2*)alloc((size_t)E * 8);
  uint32* cnt    = (uint32*)alloc((size_t)n_sents * 4);
  uint32* offs   = (uint32*)alloc((size_t)(n_sents + 1) * 4);
  uint32* cursor = (uint32*)alloc((size_t)n_sents * 4);
  float*  v3     = (float*)alloc(FEATD * 4);
  (void)ws_size; (void)n_in;

  hipMemsetAsync(cnt, 0, (size_t)n_sents * 4, stream);
  hipMemsetAsync(cursor, 0, (size_t)n_sents * 4, stream);

  k_v3<<<1, 64, 0, stream>>>(W_feat, W_attn, v3);
  k_node<<<(n_nodes + 255) / 256, 256, 0, stream>>>(h, W_fc, W_attn, z, s1, s2,
                                                    n_words, n_nodes);
  k_hist<<<(E + 255) / 256, 256, 0, stream>>>(dst, cnt, E);
  k_scan<<<1, 1024, 0, stream>>>(cnt, offs, n_sents);
  k_edge<<<(E + 255) / 256, 256, 0, stream>>>(tfidf, src, dst, s1, s2, v3,
                                              offs, cursor, pair, E);
  k_agg<<<n_sents, 256, 0, stream>>>(z, pair, offs, out);
}

// Round 3
// 479.013 us; speedup vs baseline: 1.6360x; 1.0020x over previous
//
#include <hip/hip_runtime.h>
#include <hip/hip_bf16.h>
#include <hip/hip_fp16.h>
#include <cstdint>

#define IN_DIM 128
#define OUT_DIM 64
#define FEATD 50
#define NEG_SLOPE 0.01f

typedef unsigned int uint32;

// K0: v3[j] = sum_o W_attn[128+o] * W_feat[o*FEATD+j]  (block 0)
//     + zero cnt/cursor (all blocks) -- replaces two hipMemsetAsync graph nodes
__global__ __launch_bounds__(256) void k_v3zero(const float* __restrict__ W_feat,
                                                const float* __restrict__ W_attn,
                                                float* __restrict__ v3,
                                                uint32* __restrict__ cnt,
                                                uint32* __restrict__ cursor,
                                                int n_sents) {
  int i = blockIdx.x * 256 + threadIdx.x;
  if (i < n_sents) { cnt[i] = 0u; cursor[i] = 0u; }
  if (blockIdx.x == 0 && threadIdx.x < FEATD) {
    int j = threadIdx.x;
    float s = 0.f;
    #pragma unroll
    for (int o = 0; o < OUT_DIM; ++o)
      s = fmaf(W_attn[2 * OUT_DIM + o], W_feat[o * FEATD + j], s);
    v3[j] = s;
  }
}

// K1: per node (lane = node): z row in fp16 (words), s1 = z.wa1 (words), s2 = z.wa2 (sents)
__global__ __launch_bounds__(256) void k_node(const float* __restrict__ h,
    const float* __restrict__ W_fc, const float* __restrict__ W_attn,
    __half* __restrict__ z, float* __restrict__ s1, float* __restrict__ s2,
    int n_words, int n_nodes) {
  __shared__ __align__(16) float Wl[OUT_DIM * IN_DIM];
  __shared__ float wal[2 * OUT_DIM];
  for (int i = threadIdx.x; i < OUT_DIM * IN_DIM; i += 256) Wl[i] = W_fc[i];
  if (threadIdx.x < 2 * OUT_DIM) wal[threadIdx.x] = W_attn[threadIdx.x];
  __syncthreads();

  int node = blockIdx.x * 256 + threadIdx.x;
  int nc = node < n_nodes ? node : (n_nodes - 1);
  const float* hrow = h + (size_t)nc * IN_DIM;

  float acc[OUT_DIM];
  #pragma unroll
  for (int o = 0; o < OUT_DIM; ++o) acc[o] = 0.f;

  #pragma unroll 1
  for (int c = 0; c < IN_DIM / 16; ++c) {  // 8 chunks of 16 input features
    float hk[16];
    #pragma unroll
    for (int k = 0; k < 4; ++k) {
      float4 t = *(const float4*)(hrow + c * 16 + k * 4);
      hk[k * 4 + 0] = t.x; hk[k * 4 + 1] = t.y;
      hk[k * 4 + 2] = t.z; hk[k * 4 + 3] = t.w;
    }
    #pragma unroll
    for (int o = 0; o < OUT_DIM; ++o) {
      const float4* wr = (const float4*)&Wl[o * IN_DIM + c * 16];  // uniform -> LDS broadcast
      #pragma unroll
      for (int k = 0; k < 4; ++k) {
        float4 w = wr[k];
        acc[o] = fmaf(hk[k * 4 + 0], w.x, acc[o]);
        acc[o] = fmaf(hk[k * 4 + 1], w.y, acc[o]);
        acc[o] = fmaf(hk[k * 4 + 2], w.z, acc[o]);
        acc[o] = fmaf(hk[k * 4 + 3], w.w, acc[o]);
      }
    }
  }

  if (node < n_words) {
    float s = 0.f;
    #pragma unroll
    for (int o = 0; o < OUT_DIM; ++o) s = fmaf(acc[o], wal[o], s);
    s1[node] = s;
    uint32 pk[32];
    #pragma unroll
    for (int k = 0; k < 32; ++k) {
      __half2 t = __floats2half2_rn(acc[2 * k], acc[2 * k + 1]);
      pk[k] = *(uint32*)&t;
    }
    uint4* zr4 = (uint4*)(z + (size_t)node * OUT_DIM);
    #pragma unroll
    for (int k = 0; k < 8; ++k)
      zr4[k] = make_uint4(pk[4 * k], pk[4 * k + 1], pk[4 * k + 2], pk[4 * k + 3]);
  } else if (node < n_nodes) {
    float s = 0.f;
    #pragma unroll
    for (int o = 0; o < OUT_DIM; ++o) s = fmaf(acc[o], wal[OUT_DIM + o], s);
    s2[node - n_words] = s;
  }
}

// K2: histogram of dst
__global__ __launch_bounds__(256) void k_hist(const int* __restrict__ dst,
                                              uint32* __restrict__ cnt, int E) {
  int e = blockIdx.x * 256 + threadIdx.x;
  if (e < E) atomicAdd(&cnt[dst[e]], 1u);
}

// K3: exclusive scan of cnt[0..n) -> off[0..n]
__global__ __launch_bounds__(1024) void k_scan(const uint32* __restrict__ cnt,
    uint32* __restrict__ off, int n) {
  __shared__ uint32 part[1024];
  int t = threadIdx.x;
  int CH = (n + 1023) >> 10;
  int base = t * CH;
  uint32 s = 0;
  for (int k = 0; k < CH; ++k) { int i = base + k; if (i < n) s += cnt[i]; }
  part[t] = s;
  __syncthreads();
  uint32 x = s;
  for (int d = 1; d < 1024; d <<= 1) {
    uint32 v = (t >= d) ? part[t - d] : 0u;
    __syncthreads();
    x += v;
    part[t] = x;
    __syncthreads();
  }
  uint32 run = (t > 0) ? part[t - 1] : 0u;
  for (int k = 0; k < CH; ++k) {
    int i = base + k;
    if (i < n) { off[i] = run; run += cnt[i]; }
  }
  if (t == 1023) off[n] = part[1023];
}

// K4: per edge: f = tfidf.v3 ; e = leaky(s1[src]+s2[dst]+f);
//     scatter {exp(e), src} into dst-sorted pair array
__global__ __launch_bounds__(256) void k_edge(const float* __restrict__ tfidf,
    const int* __restrict__ src, const int* __restrict__ dst,
    const float* __restrict__ s1, const float* __restrict__ s2,
    const float* __restrict__ v3, const uint32* __restrict__ off,
    uint32* __restrict__ cursor, float2* __restrict__ pair, int E) {
  __shared__ float v3l[FEATD];
  if (threadIdx.x < FEATD) v3l[threadIdx.x] = v3[threadIdx.x];
  __syncthreads();
  int e = blockIdx.x * 256 + threadIdx.x;
  if (e >= E) return;
  const float* row = tfidf + (size_t)e * FEATD;
  float f = 0.f;
  #pragma unroll
  for (int k = 0; k < FEATD / 2; ++k) {
    float2 v = *(const float2*)(row + 2 * k);
    f = fmaf(v.x, v3l[2 * k], f);
    f = fmaf(v.y, v3l[2 * k + 1], f);
  }
  int sidx = src[e], d = dst[e];
  float ev = s1[sidx] + s2[d] + f;
  ev = ev >= 0.f ? ev : NEG_SLOPE * ev;
  float exv = __expf(ev);
  uint32 p = atomicAdd(&cursor[d], 1u);
  float2 pr;
  pr.x = exv;
  pr.y = __int_as_float(sidx);
  pair[off[d] + p] = pr;
}

// K5: one wave per sentence (4 per block), no cross-wave reduction.
__global__ __launch_bounds__(256) void k_agg(const __half* __restrict__ z,
    const float2* __restrict__ pair, const uint32* __restrict__ off,
    float* __restrict__ out, int n_sents) {
  int w = threadIdx.x >> 6, lane = threadIdx.x & 63;
  int s = blockIdx.x * 4 + w;
  if (s >= n_sents) return;
  uint32 j0 = off[s], j1 = off[s + 1];

  float acc = 0.f, sa = 0.f;
  uint32 j = j0;
  for (; j + 8 <= j1; j += 8) {
    float2 p[8];
    #pragma unroll
    for (int k = 0; k < 8; ++k) p[k] = pair[j + k];
    float v[8];
    #pragma unroll
    for (int k = 0; k < 8; ++k)
      v[k] = __half2float(z[(size_t)(uint32)__float_as_int(p[k].y) * OUT_DIM + lane]);
    #pragma unroll
    for (int k = 0; k < 8; ++k) { acc = fmaf(p[k].x, v[k], acc); sa += p[k].x; }
  }
  for (; j + 4 <= j1; j += 4) {
    float2 p[4];
    #pragma unroll
    for (int k = 0; k < 4; ++k) p[k] = pair[j + k];
    float v[4];
    #pragma unroll
    for (int k = 0; k < 4; ++k)
      v[k] = __half2float(z[(size_t)(uint32)__float_as_int(p[k].y) * OUT_DIM + lane]);
    #pragma unroll
    for (int k = 0; k < 4; ++k) { acc = fmaf(p[k].x, v[k], acc); sa += p[k].x; }
  }
  for (; j < j1; ++j) {
    float2 p = pair[j];
    float v = __half2float(z[(size_t)(uint32)__float_as_int(p.y) * OUT_DIM + lane]);
    acc = fmaf(p.x, v, acc);
    sa += p.x;
  }

  out[(size_t)s * OUT_DIM + lane] = (sa > 0.f) ? (acc / sa) : 0.f;
}

extern "C" void kernel_launch(void* const* d_in, const int* in_sizes, int n_in,
                              void* d_out, int out_size, void* d_ws, size_t ws_size,
                              hipStream_t stream) {
  const float* h      = (const float*)d_in[0];
  const float* tfidf  = (const float*)d_in[1];
  const float* W_fc   = (const float*)d_in[2];
  const float* W_feat = (const float*)d_in[3];
  const float* W_attn = (const float*)d_in[4];
  const int*   src    = (const int*)d_in[5];
  const int*   dst    = (const int*)d_in[6];

  int n_nodes = in_sizes[0] / IN_DIM;   // 220000
  int E       = in_sizes[5];            // 2,000,000
  int n_sents = out_size / OUT_DIM;     // 20000
  int n_words = n_nodes - n_sents;      // 200000
  float* out = (float*)d_out;

  char* ws = (char*)d_ws;
  size_t ofs = 0;
  auto alloc = [&](size_t bytes) -> char* {
    char* p = ws + ofs;
    ofs += (bytes + 255) / 256 * 256;
    return p;
  };
  __half* z      = (__half*)alloc((size_t)n_words * OUT_DIM * 2);
  float*  s1     = (float*)alloc((size_t)n_words * 4);
  float*  s2     = (float*)alloc((size_t)n_sents * 4);
  float2* pair   = (float2*)alloc((size_t)E * 8);
  uint32* cnt    = (uint32*)alloc((size_t)n_sents * 4);
  uint32* offs   = (uint32*)alloc((size_t)(n_sents + 1) * 4);
  uint32* cursor = (uint32*)alloc((size_t)n_sents * 4);
  float*  v3     = (float*)alloc(FEATD * 4);
  (void)ws_size; (void)n_in;

  k_v3zero<<<(n_sents + 255) / 256, 256, 0, stream>>>(W_feat, W_attn, v3, cnt,
                                                      cursor, n_sents);
  k_node<<<(n_nodes + 255) / 256, 256, 0, stream>>>(h, W_fc, W_attn, z, s1, s2,
                                                    n_words, n_nodes);
  k_hist<<<(E + 255) / 256, 256, 0, stream>>>(dst, cnt, E);
  k_scan<<<1, 1024, 0, stream>>>(cnt, offs, n_sents);
  k_edge<<<(E + 255) / 256, 256, 0, stream>>>(tfidf, src, dst, s1, s2, v3,
                                              offs, cursor, pair, E);
  k_agg<<<(n_sents + 3) / 4, 256, 0, stream>>>(z, pair, offs, out, n_sents);
}